// Round 1
// 113.016 us; speedup vs baseline: 1.0679x; 1.0679x over previous
//
#include <hip/hip_runtime.h>
#include <math.h>

#define BB 512
#define DD 16
#define NN 64
#define MM 32
#define RR 32
#define CC 10
#define BBLK 16          // b's per chain block (8 waves, 2 chains/wave)
#define SS 2             // chain segments (d 0..7 | d 8..15)
#define DSEG (DD / SS)
#define ROWH 40          // halves per LDS row (80 B, 16B-aligned)
#define BREGH 1304       // halves per b region

typedef _Float16 v8h __attribute__((ext_vector_type(8)));
typedef float v4f __attribute__((ext_vector_type(4)));

union H8 { unsigned int u[4]; v8h h; _Float16 e[8]; };
union H4 { unsigned int u[2]; _Float16 e[4]; };

// ---------------------------------------------------------------------------
// Kernel 1 (merged producers, all coalesced via LDS staging):
//  blocks [0,1024):      feat_h = fp16( tensor @ W + b )   [B][D][M]
//  blocks [1024,1344):   per (c,d,half-slab): G -> gh in MFMA B-frag order
//    gh[(((c*16+d)*64 + tile)*64 + lane)*8 + r] =
//        fp16( G[c][d][i=tile>>1][m=8*(lane>>4)+r][j=16*(tile&1)+(lane&15)] )
// ---------------------------------------------------------------------------
__global__ __launch_bounds__(256) void produce_kernel(
    const float* __restrict__ tensor, const float* __restrict__ W,
    const float* __restrict__ bias,   const float* __restrict__ G,
    _Float16* __restrict__ fh,        _Float16* __restrict__ gh) {
    __shared__ __align__(16) char smem[36864];
    const int t = threadIdx.x;
    if (blockIdx.x < 1024) {
        float* ten_s = (float*)smem;          // [8][64]
        float* W_s   = (float*)smem + 512;    // [64][32]
        const int bd0 = blockIdx.x * 8;
        if (t < 128)
            *(float4*)(ten_s + t * 4) = *(const float4*)(tensor + bd0 * NN + t * 4);
        *(float4*)(W_s + t * 4)        = *(const float4*)(W + t * 4);
        *(float4*)(W_s + 1024 + t * 4) = *(const float4*)(W + 1024 + t * 4);
        __syncthreads();
        const int m = t & 31, bd_l = t >> 5;
        float acc = bias[m];
#pragma unroll
        for (int n = 0; n < NN; ++n) acc += ten_s[bd_l * NN + n] * W_s[n * MM + m];
        fh[(bd0 + bd_l) * MM + m] = (_Float16)acc;
    } else {
        _Float16* lg = (_Float16*)smem;       // [di][m][j], m-stride 36 halves
        const int pb = blockIdx.x - 1024;     // 0..319
        const int c  = pb >> 5;
        const int d  = (pb >> 1) & 15;
        const int hf = pb & 1;
        const float* src = G + (size_t)(c * DD + d) * 32768 + hf * 16384;
#pragma unroll
        for (int k = 0; k < 16; ++k) {        // coalesced read of 64 KB slab-half
            const int f = (k * 256 + t) * 4;
            float4 v = *(const float4*)(src + f);
            const int di = f >> 10, m = (f >> 5) & 31, j = f & 31;
            H4 hv;
            hv.e[0] = (_Float16)v.x; hv.e[1] = (_Float16)v.y;
            hv.e[2] = (_Float16)v.z; hv.e[3] = (_Float16)v.w;
            *(uint2*)(lg + di * 1152 + m * 36 + j) = make_uint2(hv.u[0], hv.u[1]);
        }
        __syncthreads();
#pragma unroll
        for (int k = 0; k < 8; ++k) {         // coalesced 16B fragment writes
            const int idx = k * 256 + t;
            const int tl = idx >> 6, ln = idx & 63;
            const int di = tl >> 1, jh = tl & 1;
            const int q = ln >> 4, j4 = ln & 15;
            const int j = jh * 16 + j4;
            H8 o;
#pragma unroll
            for (int r = 0; r < 8; ++r)
                o.e[r] = lg[di * 1152 + (8 * q + r) * 36 + j];
            const size_t gi = ((size_t)(c * DD + d) * 64 + hf * 32 + tl) * 64 + ln;
            *(v8h*)(gh + gi * 8) = o.h;
        }
    }
}

// ---------------------------------------------------------------------------
// Kernel 2: per (c, b-block of 16, segment s): build 16 cores per d via MFMA,
// 2 chains per wave, G fragments prefetched one d ahead.
// XCD swizzle (bid%8 heuristic): class c's 64 blocks land on one XCD so its
// ~2 MB gh working set stays L2-resident. c=8 split over XCD 2..5, c=9 over
// {6,7,0,1} -> exactly 80 blocks per XCD.
// Final products stored as fp16 (packed 16B stores via in-LDS transpose):
// s=0 row-major P0, s=1 stores P1^T row-major -> combine is elementwise dot.
// ---------------------------------------------------------------------------
__global__ __launch_bounds__(512, 4) void chain_kernel(
    const _Float16* __restrict__ feat_h,
    const _Float16* __restrict__ g_h,
    _Float16* __restrict__ segP)       // [2][C][B][32][32] fp16, s=1 transposed
{
    __shared__ __align__(16) _Float16 lds[BBLK * BREGH];  // 41728 B

    const int bid = blockIdx.x;        // 0..639
    const int xcd = bid & 7;
    const int idx = bid >> 3;          // 0..79
    int c, sub;
    if (idx < 64) { c = xcd; sub = idx; }
    else {
        const int e = idx - 64;        // 0..15
        if (xcd >= 2 && xcd <= 5) { c = 8; sub = (xcd - 2) * 16 + e; }
        else                      { c = 9; sub = (((xcd + 2) & 7)) * 16 + e; }
    }
    const int s  = sub & 1;
    const int b0 = (sub >> 1) * BBLK;
    const int d0 = s * DSEG;
    const int t    = threadIdx.x;
    const int w    = t >> 6;           // wave 0..7
    const int lane = t & 63;
    const int q    = lane >> 4;
    const int j4   = lane & 15;

    const int bA = b0 + j4;            // all 16 A rows valid
    const size_t gc = (size_t)c * DD * 32768;

    // prefetch d0 fragments
    v8h afh = *(const v8h*)(feat_h + (size_t)bA * (DD * MM) + d0 * MM + q * 8);
    v8h gf[8];
#pragma unroll
    for (int u = 0; u < 8; ++u)
        gf[u] = *(const v8h*)(g_h + gc + (size_t)d0 * 32768 +
                              ((size_t)(w * 8 + u) * 64 + lane) * 8);

    v8h pah[2][2];                     // [chain cc][mi]

    for (int dd = 0; dd < DSEG; ++dd) {
        const int d = d0 + dd;
        __syncthreads();   // WAR: previous p2 reads of lds done
        // ---- phase 1: 8 MFMAs on prefetched fragments --------------------
        v4f av[8];
#pragma unroll
        for (int u = 0; u < 8; ++u) {
            v4f z = {0.f, 0.f, 0.f, 0.f};
            av[u] = __builtin_amdgcn_mfma_f32_16x16x32_f16(afh, gf[u], z, 0, 0, 0);
        }
        if (dd < DSEG - 1) {           // prefetch d+1 (overlaps p2 + barriers)
            afh = *(const v8h*)(feat_h + (size_t)bA * (DD * MM) + (d + 1) * MM + q * 8);
            const size_t gb = gc + (size_t)(d + 1) * 32768;
#pragma unroll
            for (int u = 0; u < 8; ++u)
                gf[u] = *(const v8h*)(g_h + gb + ((size_t)(w * 8 + u) * 64 + lane) * 8);
        }
        // store cores: L[b=4q+reg][j][i], i = 4w+ii contiguous
#pragma unroll
        for (int jh = 0; jh < 2; ++jh)
#pragma unroll
            for (int reg = 0; reg < 4; ++reg) {
                H4 hv;
                hv.e[0] = (_Float16)av[0 + jh][reg];
                hv.e[1] = (_Float16)av[2 + jh][reg];
                hv.e[2] = (_Float16)av[4 + jh][reg];
                hv.e[3] = (_Float16)av[6 + jh][reg];
                *(uint2*)(&lds[(4 * q + reg) * BREGH + (16 * jh + j4) * ROWH + 4 * w]) =
                    make_uint2(hv.u[0], hv.u[1]);
            }
        __syncthreads();   // cores ready
        // ---- phase 2: wave w advances chains b = 2w, 2w+1 ----------------
#pragma unroll
        for (int cc = 0; cc < 2; ++cc) {
            const int bl = 2 * w + cc;
            _Float16* base = lds + bl * BREGH;
            if (dd == 0) {
#pragma unroll
                for (int mi = 0; mi < 2; ++mi) {
                    H8 a;
#pragma unroll
                    for (int r = 0; r < 8; ++r)
                        a.e[r] = base[(8 * q + r) * ROWH + 16 * mi + j4];
                    pah[cc][mi] = a.h;
                }
            } else {
                v8h bf[2];
#pragma unroll
                for (int ni = 0; ni < 2; ++ni)
                    bf[ni] = *(const v8h*)(base + (16 * ni + j4) * ROWH + 8 * q);
                v4f acc[2][2];
#pragma unroll
                for (int mi = 0; mi < 2; ++mi)
#pragma unroll
                    for (int ni = 0; ni < 2; ++ni) {
                        v4f z = {0.f, 0.f, 0.f, 0.f};
                        acc[mi][ni] = __builtin_amdgcn_mfma_f32_16x16x32_f16(
                            pah[cc][mi], bf[ni], z, 0, 0, 0);
                    }
                if (dd < DSEG - 1) {
#pragma unroll
                    for (int mi = 0; mi < 2; ++mi)
#pragma unroll
                        for (int ni = 0; ni < 2; ++ni)
#pragma unroll
                            for (int reg = 0; reg < 4; ++reg)
                                base[(16 * mi + 4 * q + reg) * ROWH + 16 * ni + j4] =
                                    (_Float16)acc[mi][ni][reg];
                    __builtin_amdgcn_sched_barrier(0);
#pragma unroll
                    for (int mi = 0; mi < 2; ++mi)
                        pah[cc][mi] = *(const v8h*)(base + (16 * mi + j4) * ROWH + 8 * q);
                } else {
                    // final segment product -> fp16 via in-LDS transpose,
                    // then two coalesced b128 stores per lane.
                    // Region bl is private to this wave now (its bf reads done,
                    // no other wave touches it until next launch).
                    _Float16* scr = base;
                    if (s == 0) {
                        // row-major P0: scr[row][col]
#pragma unroll
                        for (int mi = 0; mi < 2; ++mi)
#pragma unroll
                            for (int ni = 0; ni < 2; ++ni)
#pragma unroll
                                for (int reg = 0; reg < 4; ++reg)
                                    scr[(16 * mi + 4 * q + reg) * ROWH + 16 * ni + j4] =
                                        (_Float16)acc[mi][ni][reg];
                    } else {
                        // P1^T row-major: scr[col][row]
#pragma unroll
                        for (int mi = 0; mi < 2; ++mi)
#pragma unroll
                            for (int ni = 0; ni < 2; ++ni)
#pragma unroll
                                for (int reg = 0; reg < 4; ++reg)
                                    scr[(16 * ni + j4) * ROWH + 16 * mi + 4 * q + reg] =
                                        (_Float16)acc[mi][ni][reg];
                    }
                    __builtin_amdgcn_sched_barrier(0);
                    asm volatile("s_waitcnt lgkmcnt(0)" ::: "memory");
                    __builtin_amdgcn_sched_barrier(0);
                    const int rr = lane >> 1, hh = lane & 1;   // row, col-half
                    v8h lo = *(const v8h*)(scr + rr * ROWH + 16 * hh);
                    v8h hi = *(const v8h*)(scr + rr * ROWH + 16 * hh + 8);
                    _Float16* dsth = segP + ((size_t)s * CC * BB +
                                             (size_t)c * BB + (b0 + bl)) * 1024 +
                                     rr * 32 + 16 * hh;
                    *(v8h*)dsth       = lo;
                    *(v8h*)(dsth + 8) = hi;
                }
            }
        }
    }
}

// ---------------------------------------------------------------------------
// Kernel 3: fused combine + log-softmax. Wave per b, 2 waves/block so all
// 256 blocks cover the CUs:
//   tr[c] = sum_ij P0[i][j] * P1[j][i]  (P1 pre-transposed -> pure dot)
// ---------------------------------------------------------------------------
__global__ __launch_bounds__(128) void combine_lsm_kernel(
    const _Float16* __restrict__ segP, float* __restrict__ out) {
    const int t    = threadIdx.x;
    const int b    = blockIdx.x * 2 + (t >> 6);
    const int lane = t & 63;
    const _Float16* P1b = segP + (size_t)CC * BB * 1024;

    float tr[CC];
#pragma unroll
    for (int c = 0; c < CC; ++c) {
        const _Float16* p0 = segP + ((size_t)c * BB + b) * 1024 + lane * 16;
        const _Float16* p1 = P1b  + ((size_t)c * BB + b) * 1024 + lane * 16;
        v8h x0 = ((const v8h*)p0)[0];
        v8h x1 = ((const v8h*)p0)[1];
        v8h y0 = ((const v8h*)p1)[0];
        v8h y1 = ((const v8h*)p1)[1];
        float acc = 0.f;
#pragma unroll
        for (int e = 0; e < 8; ++e)
            acc += (float)x0[e] * (float)y0[e] + (float)x1[e] * (float)y1[e];
#pragma unroll
        for (int off = 32; off > 0; off >>= 1)
            acc += __shfl_xor(acc, off);
        tr[c] = acc;
    }
    float mx = -1e30f;
#pragma unroll
    for (int c = 0; c < CC; ++c) mx = fmaxf(mx, tr[c]);
    float ssum = 0.f;
#pragma unroll
    for (int c = 0; c < CC; ++c) ssum += expf(tr[c] - mx);
    const float ls = logf(ssum);
    float val = 0.f;
#pragma unroll
    for (int c = 0; c < CC; ++c) if (lane == c) val = tr[c] - mx - ls;
    if (lane < CC) out[b * CC + lane] = val;
}

// ---------------------------------------------------------------------------
extern "C" void kernel_launch(void* const* d_in, const int* in_sizes, int n_in,
                              void* d_out, int out_size, void* d_ws, size_t ws_size,
                              hipStream_t stream) {
    const float* tensor = (const float*)d_in[0];
    const float* W      = (const float*)d_in[1];
    const float* bias   = (const float*)d_in[2];
    const float* G      = (const float*)d_in[3];
    float* out = (float*)d_out;

    const size_t FEAT = (size_t)BB * DD * MM;          // 262144 halves
    const size_t GPK  = (size_t)CC * DD * 64 * 64 * 8; // 5242880 halves
    _Float16* fh = (_Float16*)d_ws;
    _Float16* gh = fh + FEAT;
    _Float16* segH = gh + GPK;                         // 2*10*512*1024 halves (20 MB)

    produce_kernel<<<1024 + 320, 256, 0, stream>>>(tensor, W, bias, G, fh, gh);
    chain_kernel<<<CC * (BB / BBLK) * SS, 512, 0, stream>>>(fh, gh, segH);
    combine_lsm_kernel<<<BB / 2, 128, 0, stream>>>(segH, out);
}